// Round 6
// baseline (279.003 us; speedup 1.0000x reference)
//
#include <hip/hip_runtime.h>
#include <math.h>

#define T_TOK 2048
#define H_DIM 1024
#define I_DIM 512
#define N_EXP 16
#define TOPK  4
#define NPAIR (T_TOK*TOPK)   /* 8192 */

typedef unsigned short u16;
typedef __attribute__((ext_vector_type(8))) short s8v;   // 8 bf16 codes (4 VGPR)
typedef __attribute__((ext_vector_type(4))) float f4v;   // MFMA accumulator

#define GLDS(g, l) __builtin_amdgcn_global_load_lds( \
    (const __attribute__((address_space(1))) void*)(g), \
    (__attribute__((address_space(3))) void*)(l), 16, 0, 0)

// ---------- fp8 e4m3fn round-trip (RNE); input must be in [-448,448] ----------
__device__ __forceinline__ float fp8_rt(float v) {
    float av = fabsf(v);
    if (av < 0.015625f) {                 // subnormal region: quantum 2^-9
        return rintf(v * 512.0f) * 0.001953125f;
    }
    unsigned u = __float_as_uint(v);
    unsigned lsb = (u >> 20) & 1u;        // keep 3 mantissa bits, RNE
    u = (u + 0x7FFFFu + lsb) & 0xFFF00000u;
    return __uint_as_float(u);
}

__device__ __forceinline__ unsigned f2bf(float v) {  // exact for fp8-representable values
    return __float_as_uint(v) >> 16;
}

// ---------- K1: x -> fp8 codes (bf16) + per-128-group scales ----------
__global__ void k_quant_x(const float* __restrict__ x, u16* __restrict__ xq,
                          float* __restrict__ xs) {
    int t = blockIdx.x, tid = threadIdx.x;
    float4 v = ((const float4*)(x + (size_t)t * H_DIM))[tid];
    float a = fmaxf(fmaxf(fabsf(v.x), fabsf(v.y)), fmaxf(fabsf(v.z), fabsf(v.w)));
    #pragma unroll
    for (int m = 16; m >= 1; m >>= 1) a = fmaxf(a, __shfl_xor(a, m));
    float s = fmaxf(a, 1e-10f) / 448.0f;
    ushort4 r;
    r.x = (u16)f2bf(fp8_rt(fminf(fmaxf(v.x / s, -448.f), 448.f)));
    r.y = (u16)f2bf(fp8_rt(fminf(fmaxf(v.y / s, -448.f), 448.f)));
    r.z = (u16)f2bf(fp8_rt(fminf(fmaxf(v.z / s, -448.f), 448.f)));
    r.w = (u16)f2bf(fp8_rt(fminf(fmaxf(v.w / s, -448.f), 448.f)));
    ((ushort4*)(xq + (size_t)t * H_DIM))[tid] = r;
    if ((tid & 31) == 0) xs[t * 8 + (tid >> 5)] = s;
}

// ---------- K2: routing lists ----------
__global__ void k_route(const int* __restrict__ idx, int* __restrict__ counts,
                        int* __restrict__ lists) {
    int p = blockIdx.x * 256 + threadIdx.x;
    if (p < NPAIR) {
        int e = idx[p];
        int pos = atomicAdd(&counts[e], 1);
        lists[e * NPAIR + pos] = p;
    }
}

// ---------- K3: gate_up MFMA GEMM, reg-staged f32 B (fused cvt), GLDS A ----------
// grid 2048 1-D: e = bid&15 (XCD pin), tile = bid>>4: tt = tile>>3 (M-tile of 64 pairs),
// it = tile&7 (64 gate cols [it*64,+64) + 64 up cols [512+it*64,+64)).
// 256 thr = 4 waves (m = w&1 row-half, q = w>>1: 0=gate cols, 1=up cols), wave-tile 32x64.
// K=1024, BK=64 (16 chunks), fold scales every 2 chunks (kb = t>>1).
// Pipeline: issue f32 B-loads(t+1)+GLDS A(t+1) BEFORE compute(t); cvt+ds_write after;
// one __syncthreads per chunk (drains A-DMA; ds_write reg-deps handle B).
__global__ __launch_bounds__(256, 3)
void k_gateup(const u16* __restrict__ xq, const float* __restrict__ xs,
              const int* __restrict__ counts, const int* __restrict__ lists,
              const float* __restrict__ wgu, const float* __restrict__ sgu,
              const u16* __restrict__ zbuf, float* __restrict__ hbuf) {
    int bid = blockIdx.x;
    int e = bid & 15, tile = bid >> 4;
    int tt = tile >> 3, it = tile & 7;
    int n = counts[e];
    if (tt * 64 >= n) return;

    __shared__ __align__(16) u16 sm[2][12288];   // per buf: B 128x64 | A 64x64 bf16 codes
    __shared__ float xs_l[64][8];
    __shared__ int ptok[64];

    int tid = threadIdx.x;
    int w = tid >> 6, lane = tid & 63;
    int m = w & 1, q = w >> 1;
    int l15 = lane & 15, l4 = lane >> 4;

    if (tid < 64) {
        int slot = tt * 64 + tid;
        ptok[tid] = (slot < n) ? lists[e * NPAIR + slot] : -1;
    }
    __syncthreads();
    {
        int r = tid >> 2, kb4 = (tid & 3) * 2;
        int p = ptok[r];
        xs_l[r][kb4]     = (p >= 0) ? xs[(p >> 2) * 8 + kb4]     : 0.f;
        xs_l[r][kb4 + 1] = (p >= 0) ? xs[(p >> 2) * 8 + kb4 + 1] : 0.f;
    }

    // ---- B reg-staging setup: thread owns 4 slots (row j*32+srow, 8 bf16 cols sc*8) ----
    const float* wf = wgu + (size_t)e * (2 * I_DIM) * H_DIM;
    int srow = tid >> 3, sc = tid & 7;
    int nrowj[4]; int dstB[4];
    #pragma unroll
    for (int j = 0; j < 4; ++j) {
        int row = j * 32 + srow;                                  // [0,128)
        nrowj[j] = (row < 64) ? it * 64 + row : 448 + it * 64 + row;  // gate | up
        dstB[j] = row * 64 + (sc ^ (srow & 7)) * 8;               // swizzled write slot
    }
    // ---- A staging via GLDS (bf16 codes, pre-swizzled source) ----
    const u16* srcA[2];
    #pragma unroll
    for (int j = 0; j < 2; ++j) {
        int s = j * 256 + tid;
        int row = s >> 3, c = s & 7, cg = c ^ (row & 7);
        int p = ptok[row];
        srcA[j] = (p >= 0) ? xq + (size_t)(p >> 2) * H_DIM + cg * 8 : zbuf;
    }

    // fragment LDS read offsets (u16 units; row stride 64 u16 = 128B, XOR swizzle)
    int idxA[2][2], idxB[4][2];
    #pragma unroll
    for (int fm = 0; fm < 2; ++fm) {
        int ar = m * 32 + fm * 16 + l15;
        #pragma unroll
        for (int kg = 0; kg < 2; ++kg)
            idxA[fm][kg] = 8192 + ar * 64 + (((kg * 4 + l4) ^ (ar & 7)) * 8);
    }
    #pragma unroll
    for (int nf = 0; nf < 4; ++nf) {
        int br = q * 64 + nf * 16 + l15;
        #pragma unroll
        for (int kg = 0; kg < 2; ++kg)
            idxB[nf][kg] = br * 64 + (((kg * 4 + l4) ^ (br & 7)) * 8);
    }

    float4 brg[8];
    auto loadB = [&](int ck) {
        #pragma unroll
        for (int j = 0; j < 4; ++j) {
            const float4* p = (const float4*)(wf + (size_t)nrowj[j] * H_DIM + ck * 64 + sc * 8);
            brg[2 * j] = p[0]; brg[2 * j + 1] = p[1];
        }
    };
    auto writeB = [&](int buf) {
        #pragma unroll
        for (int j = 0; j < 4; ++j) {
            int4 st;
            st.x = (int)(f2bf(brg[2*j].x)   | (f2bf(brg[2*j].y)   << 16));
            st.y = (int)(f2bf(brg[2*j].z)   | (f2bf(brg[2*j].w)   << 16));
            st.z = (int)(f2bf(brg[2*j+1].x) | (f2bf(brg[2*j+1].y) << 16));
            st.w = (int)(f2bf(brg[2*j+1].z) | (f2bf(brg[2*j+1].w) << 16));
            *(int4*)&sm[buf][dstB[j]] = st;
        }
    };
    auto stageA = [&](int buf, int ck) {
        #pragma unroll
        for (int j = 0; j < 2; ++j) GLDS(srcA[j] + ck * 64, &sm[buf][8192 + j * 2048 + tid * 8]);
    };

    f4v master[2][4], part[2][4];
    #pragma unroll
    for (int a = 0; a < 2; ++a)
        #pragma unroll
        for (int b = 0; b < 4; ++b) { master[a][b] = (f4v){0,0,0,0}; part[a][b] = (f4v){0,0,0,0}; }

    const float* swp = sgu + e * 64 + (q ? 4 + (it >> 1) : (it >> 1)) * 8;

    loadB(0); stageA(0, 0); writeB(0);
    __syncthreads();   // buf0 ready; xs_l/ptok published

    for (int t = 0; t < 16; ++t) {
        if (t < 15) { loadB(t + 1); stageA((t + 1) & 1, t + 1); }  // in flight across compute
        const u16* buf = &sm[t & 1][0];
        __builtin_amdgcn_s_setprio(1);
        #pragma unroll
        for (int kg = 0; kg < 2; ++kg) {
            s8v a0 = *(const s8v*)&buf[idxA[0][kg]];
            s8v a1 = *(const s8v*)&buf[idxA[1][kg]];
            #pragma unroll
            for (int nf = 0; nf < 4; ++nf) {
                s8v b = *(const s8v*)&buf[idxB[nf][kg]];
                part[0][nf] = __builtin_amdgcn_mfma_f32_16x16x32_bf16(a0, b, part[0][nf], 0, 0, 0);
                part[1][nf] = __builtin_amdgcn_mfma_f32_16x16x32_bf16(a1, b, part[1][nf], 0, 0, 0);
            }
        }
        __builtin_amdgcn_s_setprio(0);
        if (t & 1) {
            int kb = t >> 1;
            float sw = swp[kb];
            #pragma unroll
            for (int fm = 0; fm < 2; ++fm) {
                float c0 = xs_l[m * 32 + fm * 16 + l4 * 4 + 0][kb] * sw;
                float c1 = xs_l[m * 32 + fm * 16 + l4 * 4 + 1][kb] * sw;
                float c2 = xs_l[m * 32 + fm * 16 + l4 * 4 + 2][kb] * sw;
                float c3 = xs_l[m * 32 + fm * 16 + l4 * 4 + 3][kb] * sw;
                #pragma unroll
                for (int nf = 0; nf < 4; ++nf) {
                    master[fm][nf][0] += c0 * part[fm][nf][0];
                    master[fm][nf][1] += c1 * part[fm][nf][1];
                    master[fm][nf][2] += c2 * part[fm][nf][2];
                    master[fm][nf][3] += c3 * part[fm][nf][3];
                    part[fm][nf] = (f4v){0,0,0,0};
                }
            }
        }
        if (t < 15) writeB((t + 1) & 1);   // reg-dep forces vmcnt wait here (overlapped)
        __syncthreads();                   // drains A-DMA + publishes ds_writes
    }

    // epilogue: q=1 waves park up in LDS; q=0 waves fuse silu(gate)*up -> hbuf f32
    float* Ul = (float*)sm;   // [64][65]
    if (q == 1) {
        #pragma unroll
        for (int fm = 0; fm < 2; ++fm)
            #pragma unroll
            for (int nf = 0; nf < 4; ++nf)
                #pragma unroll
                for (int r = 0; r < 4; ++r)
                    Ul[(m * 32 + fm * 16 + l4 * 4 + r) * 65 + nf * 16 + l15] = master[fm][nf][r];
    }
    __syncthreads();
    if (q == 0) {
        #pragma unroll
        for (int fm = 0; fm < 2; ++fm)
            #pragma unroll
            for (int r = 0; r < 4; ++r) {
                int row = m * 32 + fm * 16 + l4 * 4 + r;
                int p = ptok[row];
                if (p < 0) continue;
                float* drow = hbuf + (size_t)p * I_DIM + it * 64;
                #pragma unroll
                for (int nf = 0; nf < 4; ++nf) {
                    float g = master[fm][nf][r];
                    float u = Ul[row * 65 + nf * 16 + l15];
                    drow[nf * 16 + l15] = (g / (1.0f + expf(-g))) * u;
                }
            }
    }
}

// ---------- K4: h -> fp8 codes (bf16) + per-128-group scales ----------
__global__ void k_quant_h(const float* __restrict__ h, u16* __restrict__ hq,
                          float* __restrict__ hs) {
    int p = blockIdx.x, tid = threadIdx.x;   // 128 threads, 4 f32 each
    float4 v = ((const float4*)(h + (size_t)p * I_DIM))[tid];
    float a = fmaxf(fmaxf(fabsf(v.x), fabsf(v.y)), fmaxf(fabsf(v.z), fabsf(v.w)));
    #pragma unroll
    for (int m = 16; m >= 1; m >>= 1) a = fmaxf(a, __shfl_xor(a, m));
    float s = fmaxf(a, 1e-10f) / 448.0f;
    ushort4 r;
    r.x = (u16)f2bf(fp8_rt(fminf(fmaxf(v.x / s, -448.f), 448.f)));
    r.y = (u16)f2bf(fp8_rt(fminf(fmaxf(v.y / s, -448.f), 448.f)));
    r.z = (u16)f2bf(fp8_rt(fminf(fmaxf(v.z / s, -448.f), 448.f)));
    r.w = (u16)f2bf(fp8_rt(fminf(fmaxf(v.w / s, -448.f), 448.f)));
    ((ushort4*)(hq + (size_t)p * I_DIM))[tid] = r;
    if ((tid & 31) == 0) hs[p * 4 + (tid >> 5)] = s;
}

// ---------- K5: down MFMA GEMM, reg-staged f32 B + rw-weighted partial write ----------
// grid 2048: e = bid&15, tile = bid>>4: tt = tile>>3, nt = tile&7 (128 H-cols).
// K=512, BK=64 (8 chunks), fold every 2 (kb = t>>1, 4 scale blocks).
__global__ __launch_bounds__(256, 3)
void k_down(const u16* __restrict__ hq, const float* __restrict__ hs,
            const int* __restrict__ counts, const int* __restrict__ lists,
            const float* __restrict__ wdn, const float* __restrict__ sdn,
            const float* __restrict__ tkw, const u16* __restrict__ zbuf,
            float* __restrict__ dout) {
    int bid = blockIdx.x;
    int e = bid & 15, tile = bid >> 4;
    int tt = tile >> 3, nt = tile & 7;
    int n = counts[e];
    if (tt * 64 >= n) return;

    __shared__ __align__(16) u16 sm[2][12288];
    __shared__ float hs_l[64][4];
    __shared__ float rw_l[64];
    __shared__ int ptok[64];

    int tid = threadIdx.x;
    int w = tid >> 6, lane = tid & 63;
    int m = w & 1, q = w >> 1;
    int l15 = lane & 15, l4 = lane >> 4;

    if (tid < 64) {
        int slot = tt * 64 + tid;
        ptok[tid] = (slot < n) ? lists[e * NPAIR + slot] : -1;
    }
    __syncthreads();
    {
        int r = tid >> 2, kb = tid & 3;
        int p = ptok[r];
        hs_l[r][kb] = (p >= 0) ? hs[p * 4 + kb] : 0.f;
        if (tid < 64) rw_l[tid] = (ptok[tid] >= 0) ? tkw[ptok[tid]] : 0.f;
    }

    const float* wf = wdn + (size_t)e * H_DIM * I_DIM;
    int srow = tid >> 3, sc = tid & 7;
    int nrowj[4]; int dstB[4];
    #pragma unroll
    for (int j = 0; j < 4; ++j) {
        int row = j * 32 + srow;
        nrowj[j] = nt * 128 + row;
        dstB[j] = row * 64 + (sc ^ (srow & 7)) * 8;
    }
    const u16* srcA[2];
    #pragma unroll
    for (int j = 0; j < 2; ++j) {
        int s = j * 256 + tid;
        int row = s >> 3, c = s & 7, cg = c ^ (row & 7);
        int p = ptok[row];
        srcA[j] = (p >= 0) ? hq + (size_t)p * I_DIM + cg * 8 : zbuf;
    }

    int idxA[2][2], idxB[4][2];
    #pragma unroll
    for (int fm = 0; fm < 2; ++fm) {
        int ar = m * 32 + fm * 16 + l15;
        #pragma unroll
        for (int kg = 0; kg < 2; ++kg)
            idxA[fm][kg] = 8192 + ar * 64 + (((kg * 4 + l4) ^ (ar & 7)) * 8);
    }
    #pragma unroll
    for (int nf = 0; nf < 4; ++nf) {
        int br = q * 64 + nf * 16 + l15;
        #pragma unroll
        for (int kg = 0; kg < 2; ++kg)
            idxB[nf][kg] = br * 64 + (((kg * 4 + l4) ^ (br & 7)) * 8);
    }

    float4 brg[8];
    auto loadB = [&](int ck) {
        #pragma unroll
        for (int j = 0; j < 4; ++j) {
            const float4* p = (const float4*)(wf + (size_t)nrowj[j] * I_DIM + ck * 64 + sc * 8);
            brg[2 * j] = p[0]; brg[2 * j + 1] = p[1];
        }
    };
    auto writeB = [&](int buf) {
        #pragma unroll
        for (int j = 0; j < 4; ++j) {
            int4 st;
            st.x = (int)(f2bf(brg[2*j].x)   | (f2bf(brg[2*j].y)   << 16));
            st.y = (int)(f2bf(brg[2*j].z)   | (f2bf(brg[2*j].w)   << 16));
            st.z = (int)(f2bf(brg[2*j+1].x) | (f2bf(brg[2*j+1].y) << 16));
            st.w = (int)(f2bf(brg[2*j+1].z) | (f2bf(brg[2*j+1].w) << 16));
            *(int4*)&sm[buf][dstB[j]] = st;
        }
    };
    auto stageA = [&](int buf, int ck) {
        #pragma unroll
        for (int j = 0; j < 2; ++j) GLDS(srcA[j] + ck * 64, &sm[buf][8192 + j * 2048 + tid * 8]);
    };

    f4v master[2][4], part[2][4];
    #pragma unroll
    for (int a = 0; a < 2; ++a)
        #pragma unroll
        for (int b = 0; b < 4; ++b) { master[a][b] = (f4v){0,0,0,0}; part[a][b] = (f4v){0,0,0,0}; }

    const float* swp = sdn + (e * 8 + nt) * 4;

    loadB(0); stageA(0, 0); writeB(0);
    __syncthreads();

    for (int t = 0; t < 8; ++t) {
        if (t < 7) { loadB(t + 1); stageA((t + 1) & 1, t + 1); }
        const u16* buf = &sm[t & 1][0];
        __builtin_amdgcn_s_setprio(1);
        #pragma unroll
        for (int kg = 0; kg < 2; ++kg) {
            s8v a0 = *(const s8v*)&buf[idxA[0][kg]];
            s8v a1 = *(const s8v*)&buf[idxA[1][kg]];
            #pragma unroll
            for (int nf = 0; nf < 4; ++nf) {
                s8v b = *(const s8v*)&buf[idxB[nf][kg]];
                part[0][nf] = __builtin_amdgcn_mfma_f32_16x16x32_bf16(a0, b, part[0][nf], 0, 0, 0);
                part[1][nf] = __builtin_amdgcn_mfma_f32_16x16x32_bf16(a1, b, part[1][nf], 0, 0, 0);
            }
        }
        __builtin_amdgcn_s_setprio(0);
        if (t & 1) {
            int kb = t >> 1;
            float sw = swp[kb];
            #pragma unroll
            for (int fm = 0; fm < 2; ++fm) {
                float c0 = hs_l[m * 32 + fm * 16 + l4 * 4 + 0][kb] * sw;
                float c1 = hs_l[m * 32 + fm * 16 + l4 * 4 + 1][kb] * sw;
                float c2 = hs_l[m * 32 + fm * 16 + l4 * 4 + 2][kb] * sw;
                float c3 = hs_l[m * 32 + fm * 16 + l4 * 4 + 3][kb] * sw;
                #pragma unroll
                for (int nf = 0; nf < 4; ++nf) {
                    master[fm][nf][0] += c0 * part[fm][nf][0];
                    master[fm][nf][1] += c1 * part[fm][nf][1];
                    master[fm][nf][2] += c2 * part[fm][nf][2];
                    master[fm][nf][3] += c3 * part[fm][nf][3];
                    part[fm][nf] = (f4v){0,0,0,0};
                }
            }
        }
        if (t < 7) writeB((t + 1) & 1);
        __syncthreads();
    }

    #pragma unroll
    for (int fm = 0; fm < 2; ++fm)
        #pragma unroll
        for (int r = 0; r < 4; ++r) {
            int row = m * 32 + fm * 16 + l4 * 4 + r;
            int p = ptok[row];
            if (p < 0) continue;
            float rw = rw_l[row];
            float* drow = dout + (size_t)p * H_DIM + nt * 128 + q * 64;
            #pragma unroll
            for (int nf = 0; nf < 4; ++nf)
                drow[nf * 16 + l15] = rw * master[fm][nf][r];
        }
}

// ---------- K6: sum the 4 slot-partials per token ----------
__global__ void k_reduce(const float* __restrict__ dout, float* __restrict__ out) {
    int i = blockIdx.x * 256 + threadIdx.x;   // f32x4 index over T*H
    int t = i >> 8, h4 = i & 255;
    const float4* d = (const float4*)dout;
    float4 a = d[(size_t)(t * 4 + 0) * 256 + h4];
    float4 b = d[(size_t)(t * 4 + 1) * 256 + h4];
    float4 c = d[(size_t)(t * 4 + 2) * 256 + h4];
    float4 e = d[(size_t)(t * 4 + 3) * 256 + h4];
    float4 r;
    r.x = a.x + b.x + c.x + e.x;
    r.y = a.y + b.y + c.y + e.y;
    r.z = a.z + b.z + c.z + e.z;
    r.w = a.w + b.w + c.w + e.w;
    ((float4*)out)[i] = r;
}

extern "C" void kernel_launch(void* const* d_in, const int* in_sizes, int n_in,
                              void* d_out, int out_size, void* d_ws, size_t ws_size,
                              hipStream_t stream) {
    const float* hs_in = (const float*)d_in[0];
    const int*   tki = (const int*)d_in[1];
    const float* tkw = (const float*)d_in[2];
    const float* wgu = (const float*)d_in[3];
    const float* sgu = (const float*)d_in[4];
    const float* wdn = (const float*)d_in[5];
    const float* sdn = (const float*)d_in[6];
    float* out = (float*)d_out;

    char* ws = (char*)d_ws;
    const size_t MB = 1024 * 1024;
    float* dout   = (float*)(ws);                  // 32 MB (NPAIR*H f32)
    u16*   xq     = (u16*)(ws + 48 * MB);          // 4 MB
    float* xs     = (float*)(ws + 52 * MB);        // 64 KB
    float* hbuf   = (float*)(ws + 53 * MB);        // 16 MB (NPAIR*I f32)
    u16*   hq     = (u16*)(ws + 69 * MB);          // 8 MB
    float* hs     = (float*)(ws + 77 * MB);        // 128 KB
    int*   counts = (int*)(ws + 78 * MB);          // 64 ints
    u16*   zbuf   = (u16*)(ws + 78 * MB + 4096);   // 4 KB zeros
    int*   lists  = (int*)(ws + 78 * MB + 65536);  // 512 KB

    hipMemsetAsync(counts, 0, 256, stream);
    hipMemsetAsync(zbuf, 0, 4096, stream);

    k_quant_x<<<T_TOK, 256, 0, stream>>>(hs_in, xq, xs);
    k_route<<<NPAIR / 256, 256, 0, stream>>>(tki, counts, lists);
    k_gateup<<<2048, 256, 0, stream>>>(xq, xs, counts, lists, wgu, sgu, zbuf, hbuf);
    k_quant_h<<<NPAIR, 128, 0, stream>>>(hbuf, hq, hs);
    k_down<<<2048, 256, 0, stream>>>(hq, hs, counts, lists, wdn, sdn, tkw, zbuf, dout);
    k_reduce<<<T_TOK * H_DIM / 1024, 256, 0, stream>>>(dout, out);
}

// Round 7
// 273.351 us; speedup vs baseline: 1.0207x; 1.0207x over previous
//
#include <hip/hip_runtime.h>
#include <math.h>

#define T_TOK 2048
#define H_DIM 1024
#define I_DIM 512
#define N_EXP 16
#define TOPK  4
#define NPAIR (T_TOK*TOPK)   /* 8192 */

typedef unsigned short u16;
typedef __attribute__((ext_vector_type(8))) short s8v;   // 8 bf16 codes (4 VGPR)
typedef __attribute__((ext_vector_type(4))) float f4v;   // MFMA accumulator

#define GLDS(g, l) __builtin_amdgcn_global_load_lds( \
    (const __attribute__((address_space(1))) void*)(g), \
    (__attribute__((address_space(3))) void*)(l), 16, 0, 0)

// ---------- fp8 e4m3fn round-trip (RNE); input must be in [-448,448] ----------
__device__ __forceinline__ float fp8_rt(float v) {
    float av = fabsf(v);
    if (av < 0.015625f) {                 // subnormal region: quantum 2^-9
        return rintf(v * 512.0f) * 0.001953125f;
    }
    unsigned u = __float_as_uint(v);
    unsigned lsb = (u >> 20) & 1u;        // keep 3 mantissa bits, RNE
    u = (u + 0x7FFFFu + lsb) & 0xFFF00000u;
    return __uint_as_float(u);
}

__device__ __forceinline__ unsigned f2bf(float v) {  // exact for fp8-representable values
    return __float_as_uint(v) >> 16;
}

// ---------- K0: f32 -> bf16 code conversion (exact), both weight tensors ----------
#define N8_GU (N_EXP * 2 * I_DIM * H_DIM / 8)   /* 2097152 */
__global__ void k_cvt(const float* __restrict__ a, u16* __restrict__ oa,
                      const float* __restrict__ b, u16* __restrict__ ob) {
    int i = blockIdx.x * 256 + threadIdx.x;   // 8 elements per thread
    const float* in = a; u16* out = oa;
    if (i >= N8_GU) { in = b; out = ob; i -= N8_GU; }
    const float4* p = (const float4*)in + (size_t)i * 2;
    float4 x = p[0], y = p[1];
    int4 st;
    st.x = (int)(f2bf(x.x) | (f2bf(x.y) << 16));
    st.y = (int)(f2bf(x.z) | (f2bf(x.w) << 16));
    st.z = (int)(f2bf(y.x) | (f2bf(y.y) << 16));
    st.w = (int)(f2bf(y.z) | (f2bf(y.w) << 16));
    ((int4*)out)[i] = st;
}

// ---------- K1: x -> fp8 codes (bf16) + per-128-group scales ----------
__global__ void k_quant_x(const float* __restrict__ x, u16* __restrict__ xq,
                          float* __restrict__ xs) {
    int t = blockIdx.x, tid = threadIdx.x;
    float4 v = ((const float4*)(x + (size_t)t * H_DIM))[tid];
    float a = fmaxf(fmaxf(fabsf(v.x), fabsf(v.y)), fmaxf(fabsf(v.z), fabsf(v.w)));
    #pragma unroll
    for (int m = 16; m >= 1; m >>= 1) a = fmaxf(a, __shfl_xor(a, m));
    float s = fmaxf(a, 1e-10f) / 448.0f;
    ushort4 r;
    r.x = (u16)f2bf(fp8_rt(fminf(fmaxf(v.x / s, -448.f), 448.f)));
    r.y = (u16)f2bf(fp8_rt(fminf(fmaxf(v.y / s, -448.f), 448.f)));
    r.z = (u16)f2bf(fp8_rt(fminf(fmaxf(v.z / s, -448.f), 448.f)));
    r.w = (u16)f2bf(fp8_rt(fminf(fmaxf(v.w / s, -448.f), 448.f)));
    ((ushort4*)(xq + (size_t)t * H_DIM))[tid] = r;
    if ((tid & 31) == 0) xs[t * 8 + (tid >> 5)] = s;
}

// ---------- K2: routing lists ----------
__global__ void k_route(const int* __restrict__ idx, int* __restrict__ counts,
                        int* __restrict__ lists) {
    int p = blockIdx.x * 256 + threadIdx.x;
    if (p < NPAIR) {
        int e = idx[p];
        int pos = atomicAdd(&counts[e], 1);
        lists[e * NPAIR + pos] = p;
    }
}

// ---------- K3: gate_up MFMA GEMM, m97 geometry (128x128 tile, 4x4 frags/wave) ----------
// grid 1024: e = bid&15 (XCD pin), tile = bid>>4: tt = tile>>3 (128-pair M-tile),
// it = tile&7 (N=128: 64 gate cols [it*64,+64) + 64 up cols [512+it*64,+64)).
// 256 thr = 4 waves: wr = w&1 (64-row half), wc = w>>1 (0=gate cols, 1=up cols).
// Wave-tile 64x64 (4x4 fragments). K=1024, BK=64 (16 chunks), double-buffered LDS,
// prefetch(t+1) before compute(t), one __syncthreads per chunk (R3-proven skeleton).
// Scale fold every 2 chunks (kb = t>>1).
__global__ __launch_bounds__(256, 2)
void k_gateup(const u16* __restrict__ xq, const float* __restrict__ xs,
              const int* __restrict__ counts, const int* __restrict__ lists,
              const u16* __restrict__ wgu, const float* __restrict__ sgu,
              const u16* __restrict__ zbuf, float* __restrict__ hbuf) {
    int bid = blockIdx.x;
    int e = bid & 15, tile = bid >> 4;
    int tt = tile >> 3, it = tile & 7;
    int n = counts[e];
    if (tt * 128 >= n) return;

    __shared__ __align__(16) u16 sm[2][16384];   // per buf: B [128][64] | A [128][64]
    __shared__ float xs_l[128][8];
    __shared__ int ptok[128];

    int tid = threadIdx.x;
    int w = tid >> 6, lane = tid & 63;
    int wr = w & 1, wc = w >> 1;
    int l15 = lane & 15, l4 = lane >> 4;

    if (tid < 128) {
        int slot = tt * 128 + tid;
        ptok[tid] = (slot < n) ? lists[e * NPAIR + slot] : -1;
    }
    __syncthreads();
    {
        int base = tid * 4, r = base >> 3, kb = base & 7;
        int p = ptok[r];
        #pragma unroll
        for (int i = 0; i < 4; ++i)
            xs_l[r][kb + i] = (p >= 0) ? xs[(p >> 2) * 8 + kb + i] : 0.f;
    }

    // staging sources (pre-swizzled global cols; LDS dest linear)
    const u16* wbase = wgu + (size_t)e * 1024 * 1024;
    const u16* srcB[4];
    #pragma unroll
    for (int j = 0; j < 4; ++j) {
        int s = j * 256 + tid;
        int row = s >> 3, c = s & 7, cg = c ^ (row & 7);
        int nrow = (row < 64) ? it * 64 + row : 448 + it * 64 + row;  // gate | up
        srcB[j] = wbase + (size_t)nrow * H_DIM + cg * 8;
    }
    const u16* srcA[4];
    #pragma unroll
    for (int j = 0; j < 4; ++j) {
        int s = j * 256 + tid;
        int row = s >> 3, c = s & 7, cg = c ^ (row & 7);
        int p = ptok[row];
        srcA[j] = (p >= 0) ? xq + (size_t)(p >> 2) * H_DIM + cg * 8 : zbuf;
    }

    // fragment LDS offsets (u16 units; row stride 64 u16 = 128 B, XOR slot swizzle)
    int idxA[4][2], idxB[4][2];
    #pragma unroll
    for (int fr = 0; fr < 4; ++fr) {
        int ar = wr * 64 + fr * 16 + l15;
        #pragma unroll
        for (int kg = 0; kg < 2; ++kg)
            idxA[fr][kg] = 8192 + ar * 64 + (((kg * 4 + l4) ^ (ar & 7)) * 8);
    }
    #pragma unroll
    for (int nc = 0; nc < 4; ++nc) {
        int br = wc * 64 + nc * 16 + l15;
        #pragma unroll
        for (int kg = 0; kg < 2; ++kg)
            idxB[nc][kg] = br * 64 + (((kg * 4 + l4) ^ (br & 7)) * 8);
    }

    auto stage = [&](int buf, int ck) {
        #pragma unroll
        for (int j = 0; j < 4; ++j) GLDS(srcB[j] + ck * 64, &sm[buf][(j * 256 + tid) * 8]);
        #pragma unroll
        for (int j = 0; j < 4; ++j) GLDS(srcA[j] + ck * 64, &sm[buf][8192 + (j * 256 + tid) * 8]);
    };

    f4v master[4][4], part[4][4];
    #pragma unroll
    for (int a = 0; a < 4; ++a)
        #pragma unroll
        for (int b = 0; b < 4; ++b) { master[a][b] = (f4v){0,0,0,0}; part[a][b] = (f4v){0,0,0,0}; }

    const float* swp = sgu + e * 64 + (wc ? 4 + (it >> 1) : (it >> 1)) * 8;

    stage(0, 0);
    __syncthreads();

    for (int t = 0; t < 16; ++t) {
        if (t < 15) stage((t + 1) & 1, t + 1);   // in flight across compute
        const u16* buf = &sm[t & 1][0];
        #pragma unroll
        for (int kg = 0; kg < 2; ++kg) {
            s8v a[4];
            #pragma unroll
            for (int fr = 0; fr < 4; ++fr) a[fr] = *(const s8v*)&buf[idxA[fr][kg]];
            #pragma unroll
            for (int nc = 0; nc < 4; ++nc) {
                s8v b = *(const s8v*)&buf[idxB[nc][kg]];
                #pragma unroll
                for (int fr = 0; fr < 4; ++fr)
                    part[fr][nc] = __builtin_amdgcn_mfma_f32_16x16x32_bf16(a[fr], b, part[fr][nc], 0, 0, 0);
            }
        }
        if (t & 1) {
            int kb = t >> 1;
            float sw = swp[kb];
            #pragma unroll
            for (int fr = 0; fr < 4; ++fr) {
                #pragma unroll
                for (int r = 0; r < 4; ++r) {
                    float c = xs_l[wr * 64 + fr * 16 + l4 * 4 + r][kb] * sw;
                    #pragma unroll
                    for (int nc = 0; nc < 4; ++nc) {
                        master[fr][nc][r] += c * part[fr][nc][r];
                        part[fr][nc][r] = 0.f;
                    }
                }
            }
        }
        __syncthreads();   // drains GLDS (overlapped by compute) + read/write fence
    }

    // epilogue: wc=1 waves park up in LDS; wc=0 waves fuse silu(gate)*up -> hbuf f32
    float* Ul = (float*)sm;   // [128][66] f32 = 33792 B
    if (wc == 1) {
        #pragma unroll
        for (int fr = 0; fr < 4; ++fr)
            #pragma unroll
            for (int nc = 0; nc < 4; ++nc)
                #pragma unroll
                for (int r = 0; r < 4; ++r)
                    Ul[(wr * 64 + fr * 16 + l4 * 4 + r) * 66 + nc * 16 + l15] = master[fr][nc][r];
    }
    __syncthreads();
    if (wc == 0) {
        #pragma unroll
        for (int fr = 0; fr < 4; ++fr)
            #pragma unroll
            for (int r = 0; r < 4; ++r) {
                int row = wr * 64 + fr * 16 + l4 * 4 + r;
                int p = ptok[row];
                if (p < 0) continue;
                float* drow = hbuf + (size_t)p * I_DIM + it * 64;
                #pragma unroll
                for (int nc = 0; nc < 4; ++nc) {
                    float g = master[fr][nc][r];
                    float u = Ul[row * 66 + nc * 16 + l15];
                    drow[nc * 16 + l15] = (g / (1.0f + expf(-g))) * u;
                }
            }
    }
}

// ---------- K4: h -> fp8 codes (bf16) + per-128-group scales ----------
__global__ void k_quant_h(const float* __restrict__ h, u16* __restrict__ hq,
                          float* __restrict__ hs) {
    int p = blockIdx.x, tid = threadIdx.x;   // 128 threads, 4 f32 each
    float4 v = ((const float4*)(h + (size_t)p * I_DIM))[tid];
    float a = fmaxf(fmaxf(fabsf(v.x), fabsf(v.y)), fmaxf(fabsf(v.z), fabsf(v.w)));
    #pragma unroll
    for (int m = 16; m >= 1; m >>= 1) a = fmaxf(a, __shfl_xor(a, m));
    float s = fmaxf(a, 1e-10f) / 448.0f;
    ushort4 r;
    r.x = (u16)f2bf(fp8_rt(fminf(fmaxf(v.x / s, -448.f), 448.f)));
    r.y = (u16)f2bf(fp8_rt(fminf(fmaxf(v.y / s, -448.f), 448.f)));
    r.z = (u16)f2bf(fp8_rt(fminf(fmaxf(v.z / s, -448.f), 448.f)));
    r.w = (u16)f2bf(fp8_rt(fminf(fmaxf(v.w / s, -448.f), 448.f)));
    ((ushort4*)(hq + (size_t)p * I_DIM))[tid] = r;
    if ((tid & 31) == 0) hs[p * 4 + (tid >> 5)] = s;
}

// ---------- K5: down MFMA GEMM (same geometry) + rw-weighted partial write ----------
// grid 1024: e = bid&15, tile = bid>>4: tt = tile>>3 (128 pairs), nt = tile&7 (128 H-cols).
// K=512, BK=64 (8 chunks), fold every 2 (kb = t>>1, 4 scale blocks).
__global__ __launch_bounds__(256, 2)
void k_down(const u16* __restrict__ hq, const float* __restrict__ hs,
            const int* __restrict__ counts, const int* __restrict__ lists,
            const u16* __restrict__ wdn, const float* __restrict__ sdn,
            const float* __restrict__ tkw, const u16* __restrict__ zbuf,
            float* __restrict__ dout) {
    int bid = blockIdx.x;
    int e = bid & 15, tile = bid >> 4;
    int tt = tile >> 3, nt = tile & 7;
    int n = counts[e];
    if (tt * 128 >= n) return;

    __shared__ __align__(16) u16 sm[2][16384];
    __shared__ float hs_l[128][4];
    __shared__ float rw_l[128];
    __shared__ int ptok[128];

    int tid = threadIdx.x;
    int w = tid >> 6, lane = tid & 63;
    int wr = w & 1, wc = w >> 1;
    int l15 = lane & 15, l4 = lane >> 4;

    if (tid < 128) {
        int slot = tt * 128 + tid;
        ptok[tid] = (slot < n) ? lists[e * NPAIR + slot] : -1;
    }
    __syncthreads();
    {
        int base = tid * 2, r = base >> 2, kb = base & 3;
        int p = ptok[r];
        hs_l[r][kb]     = (p >= 0) ? hs[p * 4 + kb]     : 0.f;
        hs_l[r][kb + 1] = (p >= 0) ? hs[p * 4 + kb + 1] : 0.f;
        if (tid < 128) rw_l[tid] = (ptok[tid] >= 0) ? tkw[ptok[tid]] : 0.f;
    }

    const u16* wbase = wdn + (size_t)e * H_DIM * I_DIM;
    const u16* srcB[4];
    #pragma unroll
    for (int j = 0; j < 4; ++j) {
        int s = j * 256 + tid;
        int row = s >> 3, c = s & 7, cg = c ^ (row & 7);
        srcB[j] = wbase + (size_t)(nt * 128 + row) * I_DIM + cg * 8;
    }
    const u16* srcA[4];
    #pragma unroll
    for (int j = 0; j < 4; ++j) {
        int s = j * 256 + tid;
        int row = s >> 3, c = s & 7, cg = c ^ (row & 7);
        int p = ptok[row];
        srcA[j] = (p >= 0) ? hq + (size_t)p * I_DIM + cg * 8 : zbuf;
    }

    int idxA[4][2], idxB[4][2];
    #pragma unroll
    for (int fr = 0; fr < 4; ++fr) {
        int ar = wr * 64 + fr * 16 + l15;
        #pragma unroll
        for (int kg = 0; kg < 2; ++kg)
            idxA[fr][kg] = 8192 + ar * 64 + (((kg * 4 + l4) ^ (ar & 7)) * 8);
    }
    #pragma unroll
    for (int nc = 0; nc < 4; ++nc) {
        int br = wc * 64 + nc * 16 + l15;
        #pragma unroll
        for (int kg = 0; kg < 2; ++kg)
            idxB[nc][kg] = br * 64 + (((kg * 4 + l4) ^ (br & 7)) * 8);
    }

    auto stage = [&](int buf, int ck) {
        #pragma unroll
        for (int j = 0; j < 4; ++j) GLDS(srcB[j] + ck * 64, &sm[buf][(j * 256 + tid) * 8]);
        #pragma unroll
        for (int j = 0; j < 4; ++j) GLDS(srcA[j] + ck * 64, &sm[buf][8192 + (j * 256 + tid) * 8]);
    };

    f4v master[4][4], part[4][4];
    #pragma unroll
    for (int a = 0; a < 4; ++a)
        #pragma unroll
        for (int b = 0; b < 4; ++b) { master[a][b] = (f4v){0,0,0,0}; part[a][b] = (f4v){0,0,0,0}; }

    const float* swp = sdn + (e * 8 + nt) * 4;

    stage(0, 0);
    __syncthreads();

    for (int t = 0; t < 8; ++t) {
        if (t < 7) stage((t + 1) & 1, t + 1);
        const u16* buf = &sm[t & 1][0];
        #pragma unroll
        for (int kg = 0; kg < 2; ++kg) {
            s8v a[4];
            #pragma unroll
            for (int fr = 0; fr < 4; ++fr) a[fr] = *(const s8v*)&buf[idxA[fr][kg]];
            #pragma unroll
            for (int nc = 0; nc < 4; ++nc) {
                s8v b = *(const s8v*)&buf[idxB[nc][kg]];
                #pragma unroll
                for (int fr = 0; fr < 4; ++fr)
                    part[fr][nc] = __builtin_amdgcn_mfma_f32_16x16x32_bf16(a[fr], b, part[fr][nc], 0, 0, 0);
            }
        }
        if (t & 1) {
            int kb = t >> 1;
            float sw = swp[kb];
            #pragma unroll
            for (int fr = 0; fr < 4; ++fr) {
                #pragma unroll
                for (int r = 0; r < 4; ++r) {
                    float c = hs_l[wr * 64 + fr * 16 + l4 * 4 + r][kb] * sw;
                    #pragma unroll
                    for (int nc = 0; nc < 4; ++nc) {
                        master[fr][nc][r] += c * part[fr][nc][r];
                        part[fr][nc][r] = 0.f;
                    }
                }
            }
        }
        __syncthreads();
    }

    #pragma unroll
    for (int fr = 0; fr < 4; ++fr)
        #pragma unroll
        for (int r = 0; r < 4; ++r) {
            int row = wr * 64 + fr * 16 + l4 * 4 + r;
            int p = ptok[row];
            if (p < 0) continue;
            float rw = rw_l[row];
            float* drow = dout + (size_t)p * H_DIM + nt * 128 + wc * 64;
            #pragma unroll
            for (int nc = 0; nc < 4; ++nc)
                drow[nc * 16 + l15] = rw * master[fr][nc][r];
        }
}

// ---------- K6: sum the 4 slot-partials per token ----------
__global__ void k_reduce(const float* __restrict__ dout, float* __restrict__ out) {
    int i = blockIdx.x * 256 + threadIdx.x;   // f32x4 index over T*H
    int t = i >> 8, h4 = i & 255;
    const float4* d = (const float4*)dout;
    float4 a = d[(size_t)(t * 4 + 0) * 256 + h4];
    float4 b = d[(size_t)(t * 4 + 1) * 256 + h4];
    float4 c = d[(size_t)(t * 4 + 2) * 256 + h4];
    float4 e = d[(size_t)(t * 4 + 3) * 256 + h4];
    float4 r;
    r.x = a.x + b.x + c.x + e.x;
    r.y = a.y + b.y + c.y + e.y;
    r.z = a.z + b.z + c.z + e.z;
    r.w = a.w + b.w + c.w + e.w;
    ((float4*)out)[i] = r;
}

extern "C" void kernel_launch(void* const* d_in, const int* in_sizes, int n_in,
                              void* d_out, int out_size, void* d_ws, size_t ws_size,
                              hipStream_t stream) {
    const float* hs_in = (const float*)d_in[0];
    const int*   tki = (const int*)d_in[1];
    const float* tkw = (const float*)d_in[2];
    const float* wgu = (const float*)d_in[3];
    const float* sgu = (const float*)d_in[4];
    const float* wdn = (const float*)d_in[5];
    const float* sdn = (const float*)d_in[6];
    float* out = (float*)d_out;

    char* ws = (char*)d_ws;
    const size_t MB = 1024 * 1024;
    u16*   wgu_bf = (u16*)(ws);                    // 32 MB; ALIASED by dout after k_gateup
    float* dout   = (float*)(ws);                  // 32 MB (NPAIR*H f32)
    u16*   wdn_bf = (u16*)(ws + 32 * MB);          // 16 MB
    u16*   xq     = (u16*)(ws + 48 * MB);          // 4 MB
    float* xs     = (float*)(ws + 52 * MB);        // 64 KB
    float* hbuf   = (float*)(ws + 53 * MB);        // 16 MB (NPAIR*I f32)
    u16*   hq     = (u16*)(ws + 69 * MB);          // 8 MB
    float* hs     = (float*)(ws + 77 * MB);        // 128 KB
    int*   counts = (int*)(ws + 78 * MB);          // 64 ints
    u16*   zbuf   = (u16*)(ws + 78 * MB + 4096);   // 4 KB zeros
    int*   lists  = (int*)(ws + 78 * MB + 65536);  // 512 KB

    hipMemsetAsync(counts, 0, 256, stream);
    hipMemsetAsync(zbuf, 0, 4096, stream);

    k_cvt<<<12288, 256, 0, stream>>>(wgu, wgu_bf, wdn, wdn_bf);
    k_quant_x<<<T_TOK, 256, 0, stream>>>(hs_in, xq, xs);
    k_route<<<NPAIR / 256, 256, 0, stream>>>(tki, counts, lists);
    k_gateup<<<1024, 256, 0, stream>>>(xq, xs, counts, lists, wgu_bf, sgu, zbuf, hbuf);
    k_quant_h<<<NPAIR, 128, 0, stream>>>(hbuf, hq, hs);
    k_down<<<1024, 256, 0, stream>>>(hq, hs, counts, lists, wdn_bf, sdn, tkw, zbuf, dout);
    k_reduce<<<T_TOK * H_DIM / 1024, 256, 0, stream>>>(dout, out);
}

// Round 8
// 248.947 us; speedup vs baseline: 1.1207x; 1.0980x over previous
//
#include <hip/hip_runtime.h>
#include <math.h>

#define T_TOK 2048
#define H_DIM 1024
#define I_DIM 512
#define N_EXP 16
#define TOPK  4
#define NPAIR (T_TOK*TOPK)   /* 8192 */

typedef unsigned short u16;
typedef __attribute__((ext_vector_type(8))) short s8v;   // 8 bf16 codes (4 VGPR)
typedef __attribute__((ext_vector_type(4))) float f4v;   // MFMA accumulator

#define GLDS(g, l) __builtin_amdgcn_global_load_lds( \
    (const __attribute__((address_space(1))) void*)(g), \
    (__attribute__((address_space(3))) void*)(l), 16, 0, 0)

// ---------- fp8 e4m3fn round-trip (RNE); input must be in [-448,448] ----------
__device__ __forceinline__ float fp8_rt(float v) {
    float av = fabsf(v);
    if (av < 0.015625f) {                 // subnormal region: quantum 2^-9
        return rintf(v * 512.0f) * 0.001953125f;
    }
    unsigned u = __float_as_uint(v);
    unsigned lsb = (u >> 20) & 1u;        // keep 3 mantissa bits, RNE
    u = (u + 0x7FFFFu + lsb) & 0xFFF00000u;
    return __uint_as_float(u);
}

__device__ __forceinline__ unsigned f2bf(float v) {  // exact for fp8-representable values
    return __float_as_uint(v) >> 16;
}

// ---------- K0: prep = weight cvt (f32 -> bf16 codes) + x quant + routing ----------
// blocks [0, 12288): cvt both weight tensors (8 elems/thread).
// blocks [12288, 14336): token t = bid-12288: quant x row t; threads 0-3 route pairs.
#define N8_GU (N_EXP * 2 * I_DIM * H_DIM / 8)   /* 2097152 */
__global__ void k_prep(const float* __restrict__ wgu, u16* __restrict__ wgu_bf,
                       const float* __restrict__ wdn, u16* __restrict__ wdn_bf,
                       const float* __restrict__ x, u16* __restrict__ xq,
                       float* __restrict__ xs, const int* __restrict__ tki,
                       int* __restrict__ counts, int* __restrict__ lists) {
    int bid = blockIdx.x, tid = threadIdx.x;
    if (bid < 12288) {
        int i = bid * 256 + tid;
        const float* in = wgu; u16* out = wgu_bf;
        if (i >= N8_GU) { in = wdn; out = wdn_bf; i -= N8_GU; }
        const float4* p = (const float4*)in + (size_t)i * 2;
        float4 a = p[0], b = p[1];
        int4 st;
        st.x = (int)(f2bf(a.x) | (f2bf(a.y) << 16));
        st.y = (int)(f2bf(a.z) | (f2bf(a.w) << 16));
        st.z = (int)(f2bf(b.x) | (f2bf(b.y) << 16));
        st.w = (int)(f2bf(b.z) | (f2bf(b.w) << 16));
        ((int4*)out)[i] = st;
    } else {
        int t = bid - 12288;
        if (tid < 4) {                       // routing for token t's 4 slots
            int p = t * 4 + tid;
            int e = tki[p];
            int pos = atomicAdd(&counts[e], 1);
            lists[e * NPAIR + pos] = p;
        }
        float4 v = ((const float4*)(x + (size_t)t * H_DIM))[tid];
        float a = fmaxf(fmaxf(fabsf(v.x), fabsf(v.y)), fmaxf(fabsf(v.z), fabsf(v.w)));
        #pragma unroll
        for (int m = 16; m >= 1; m >>= 1) a = fmaxf(a, __shfl_xor(a, m));
        float s = fmaxf(a, 1e-10f) / 448.0f;
        ushort4 r;
        r.x = (u16)f2bf(fp8_rt(fminf(fmaxf(v.x / s, -448.f), 448.f)));
        r.y = (u16)f2bf(fp8_rt(fminf(fmaxf(v.y / s, -448.f), 448.f)));
        r.z = (u16)f2bf(fp8_rt(fminf(fmaxf(v.z / s, -448.f), 448.f)));
        r.w = (u16)f2bf(fp8_rt(fminf(fmaxf(v.w / s, -448.f), 448.f)));
        ((ushort4*)(xq + (size_t)t * H_DIM))[tid] = r;
        if ((tid & 31) == 0) xs[t * 8 + (tid >> 5)] = s;
    }
}

// ---------- K3: gate_up MFMA GEMM (R3-proven: 64x128 tile, dbuf, 1 sync/chunk) ----------
// grid 2048 1-D: e = bid&15 (XCD pin), tile = bid>>4: tt = tile>>3 (M-tile of 64 pairs),
// it = tile&7 (64 gate cols [it*64,+64) + 64 up cols [512+it*64,+64)).
// 256 thr = 4 waves (m = w&1 row-half, q = w>>1: 0=gate cols, 1=up cols), wave-tile 32x64.
// K=1024, BK=64 (16 chunks), fold scales every 2 chunks (kb = t>>1).
__global__ __launch_bounds__(256, 3)
void k_gateup(const u16* __restrict__ xq, const float* __restrict__ xs,
              const int* __restrict__ counts, const int* __restrict__ lists,
              const u16* __restrict__ wgu, const float* __restrict__ sgu,
              const u16* __restrict__ zbuf, float* __restrict__ hbuf) {
    int bid = blockIdx.x;
    int e = bid & 15, tile = bid >> 4;
    int tt = tile >> 3, it = tile & 7;
    int n = counts[e];
    if (tt * 64 >= n) return;

    __shared__ __align__(16) u16 sm[2][12288];   // per buf: B 1024 slots | A 512 slots (24 KB)
    __shared__ float xs_l[64][8];
    __shared__ int ptok[64];

    int tid = threadIdx.x;
    int w = tid >> 6, lane = tid & 63;
    int m = w & 1, q = w >> 1;
    int l15 = lane & 15, l4 = lane >> 4;

    if (tid < 64) {
        int slot = tt * 64 + tid;
        ptok[tid] = (slot < n) ? lists[e * NPAIR + slot] : -1;
    }
    __syncthreads();
    {
        int r = tid >> 2, kb4 = (tid & 3) * 2;
        int p = ptok[r];
        xs_l[r][kb4]     = (p >= 0) ? xs[(p >> 2) * 8 + kb4]     : 0.f;
        xs_l[r][kb4 + 1] = (p >= 0) ? xs[(p >> 2) * 8 + kb4 + 1] : 0.f;
    }

    // stage-source precompute (pre-swizzled global addresses; LDS dest stays linear)
    const u16* wbase = wgu + (size_t)e * 1024 * 1024;
    const u16* srcB[4];
    #pragma unroll
    for (int j = 0; j < 4; ++j) {
        int s = j * 256 + tid;
        int row = s >> 3, c = s & 7, cg = c ^ (row & 7);
        int nrow = (row < 64) ? it * 64 + row : 448 + it * 64 + row;  // gate | up
        srcB[j] = wbase + (size_t)nrow * H_DIM + cg * 8;
    }
    const u16* srcA[2];
    #pragma unroll
    for (int j = 0; j < 2; ++j) {
        int s = j * 256 + tid;
        int row = s >> 3, c = s & 7, cg = c ^ (row & 7);
        int p = ptok[row];
        srcA[j] = (p >= 0) ? xq + (size_t)(p >> 2) * H_DIM + cg * 8 : zbuf;
    }

    // fragment LDS read offsets (u16 units; row stride 64 u16 = 128B, XOR swizzle)
    int idxA[2][2], idxB[4][2];
    #pragma unroll
    for (int fm = 0; fm < 2; ++fm) {
        int ar = m * 32 + fm * 16 + l15;
        #pragma unroll
        for (int kg = 0; kg < 2; ++kg)
            idxA[fm][kg] = 8192 + ar * 64 + (((kg * 4 + l4) ^ (ar & 7)) * 8);
    }
    #pragma unroll
    for (int nf = 0; nf < 4; ++nf) {
        int br = q * 64 + nf * 16 + l15;
        #pragma unroll
        for (int kg = 0; kg < 2; ++kg)
            idxB[nf][kg] = br * 64 + (((kg * 4 + l4) ^ (br & 7)) * 8);
    }

    auto stage = [&](int buf) {
        #pragma unroll
        for (int j = 0; j < 4; ++j) { GLDS(srcB[j], &sm[buf][j * 2048 + tid * 8]); srcB[j] += 64; }
        #pragma unroll
        for (int j = 0; j < 2; ++j) { GLDS(srcA[j], &sm[buf][8192 + j * 2048 + tid * 8]); srcA[j] += 64; }
    };

    f4v master[2][4], part[2][4];
    #pragma unroll
    for (int a = 0; a < 2; ++a)
        #pragma unroll
        for (int b = 0; b < 4; ++b) { master[a][b] = (f4v){0,0,0,0}; part[a][b] = (f4v){0,0,0,0}; }

    const float* swp = sgu + e * 64 + (q ? 4 + (it >> 1) : (it >> 1)) * 8;

    stage(0);
    __syncthreads();

    for (int t = 0; t < 16; ++t) {
        if (t < 15) stage((t + 1) & 1);
        const u16* buf = &sm[t & 1][0];
        #pragma unroll
        for (int kg = 0; kg < 2; ++kg) {
            s8v a0 = *(const s8v*)&buf[idxA[0][kg]];
            s8v a1 = *(const s8v*)&buf[idxA[1][kg]];
            #pragma unroll
            for (int nf = 0; nf < 4; ++nf) {
                s8v b = *(const s8v*)&buf[idxB[nf][kg]];
                part[0][nf] = __builtin_amdgcn_mfma_f32_16x16x32_bf16(a0, b, part[0][nf], 0, 0, 0);
                part[1][nf] = __builtin_amdgcn_mfma_f32_16x16x32_bf16(a1, b, part[1][nf], 0, 0, 0);
            }
        }
        if (t & 1) {
            int kb = t >> 1;
            float sw = swp[kb];
            #pragma unroll
            for (int fm = 0; fm < 2; ++fm) {
                float c0 = xs_l[m * 32 + fm * 16 + l4 * 4 + 0][kb] * sw;
                float c1 = xs_l[m * 32 + fm * 16 + l4 * 4 + 1][kb] * sw;
                float c2 = xs_l[m * 32 + fm * 16 + l4 * 4 + 2][kb] * sw;
                float c3 = xs_l[m * 32 + fm * 16 + l4 * 4 + 3][kb] * sw;
                #pragma unroll
                for (int nf = 0; nf < 4; ++nf) {
                    master[fm][nf][0] += c0 * part[fm][nf][0];
                    master[fm][nf][1] += c1 * part[fm][nf][1];
                    master[fm][nf][2] += c2 * part[fm][nf][2];
                    master[fm][nf][3] += c3 * part[fm][nf][3];
                    part[fm][nf] = (f4v){0,0,0,0};
                }
            }
        }
        __syncthreads();
    }

    // epilogue: q=1 waves park up in LDS; q=0 waves fuse silu(gate)*up -> hbuf f32
    float* Ul = (float*)sm;   // [64][65]
    if (q == 1) {
        #pragma unroll
        for (int fm = 0; fm < 2; ++fm)
            #pragma unroll
            for (int nf = 0; nf < 4; ++nf)
                #pragma unroll
                for (int r = 0; r < 4; ++r)
                    Ul[(m * 32 + fm * 16 + l4 * 4 + r) * 65 + nf * 16 + l15] = master[fm][nf][r];
    }
    __syncthreads();
    if (q == 0) {
        #pragma unroll
        for (int fm = 0; fm < 2; ++fm)
            #pragma unroll
            for (int r = 0; r < 4; ++r) {
                int row = m * 32 + fm * 16 + l4 * 4 + r;
                int p = ptok[row];
                if (p < 0) continue;
                float* drow = hbuf + (size_t)p * I_DIM + it * 64;
                #pragma unroll
                for (int nf = 0; nf < 4; ++nf) {
                    float g = master[fm][nf][r];
                    float u = Ul[row * 65 + nf * 16 + l15];
                    drow[nf * 16 + l15] = (g / (1.0f + expf(-g))) * u;
                }
            }
    }
}

// ---------- K4: h -> fp8 codes (bf16) + per-128-group scales ----------
__global__ void k_quant_h(const float* __restrict__ h, u16* __restrict__ hq,
                          float* __restrict__ hs) {
    int p = blockIdx.x, tid = threadIdx.x;   // 128 threads, 4 f32 each
    float4 v = ((const float4*)(h + (size_t)p * I_DIM))[tid];
    float a = fmaxf(fmaxf(fabsf(v.x), fabsf(v.y)), fmaxf(fabsf(v.z), fabsf(v.w)));
    #pragma unroll
    for (int m = 16; m >= 1; m >>= 1) a = fmaxf(a, __shfl_xor(a, m));
    float s = fmaxf(a, 1e-10f) / 448.0f;
    ushort4 r;
    r.x = (u16)f2bf(fp8_rt(fminf(fmaxf(v.x / s, -448.f), 448.f)));
    r.y = (u16)f2bf(fp8_rt(fminf(fmaxf(v.y / s, -448.f), 448.f)));
    r.z = (u16)f2bf(fp8_rt(fminf(fmaxf(v.z / s, -448.f), 448.f)));
    r.w = (u16)f2bf(fp8_rt(fminf(fmaxf(v.w / s, -448.f), 448.f)));
    ((ushort4*)(hq + (size_t)p * I_DIM))[tid] = r;
    if ((tid & 31) == 0) hs[p * 4 + (tid >> 5)] = s;
}

// ---------- K5: down MFMA GEMM (R3-proven) + rw-weighted partial write ----------
// grid 2048: e = bid&15, tile = bid>>4: tt = tile>>3, nt = tile&7 (128 H-cols).
// K=512, BK=64 (8 chunks), fold every 2 (kb = t>>1, 4 scale blocks).
__global__ __launch_bounds__(256, 3)
void k_down(const u16* __restrict__ hq, const float* __restrict__ hs,
            const int* __restrict__ counts, const int* __restrict__ lists,
            const u16* __restrict__ wdn, const float* __restrict__ sdn,
            const float* __restrict__ tkw, const u16* __restrict__ zbuf,
            float* __restrict__ dout) {
    int bid = blockIdx.x;
    int e = bid & 15, tile = bid >> 4;
    int tt = tile >> 3, nt = tile & 7;
    int n = counts[e];
    if (tt * 64 >= n) return;

    __shared__ __align__(16) u16 sm[2][12288];
    __shared__ float hs_l[64][4];
    __shared__ float rw_l[64];
    __shared__ int ptok[64];

    int tid = threadIdx.x;
    int w = tid >> 6, lane = tid & 63;
    int m = w & 1, q = w >> 1;
    int l15 = lane & 15, l4 = lane >> 4;

    if (tid < 64) {
        int slot = tt * 64 + tid;
        ptok[tid] = (slot < n) ? lists[e * NPAIR + slot] : -1;
    }
    __syncthreads();
    {
        int r = tid >> 2, kb = tid & 3;
        int p = ptok[r];
        hs_l[r][kb] = (p >= 0) ? hs[p * 4 + kb] : 0.f;
        if (tid < 64) rw_l[tid] = (ptok[tid] >= 0) ? tkw[ptok[tid]] : 0.f;
    }

    const u16* wbase = wdn + (size_t)e * H_DIM * I_DIM;
    const u16* srcB[4];
    #pragma unroll
    for (int j = 0; j < 4; ++j) {
        int s = j * 256 + tid;
        int row = s >> 3, c = s & 7, cg = c ^ (row & 7);
        srcB[j] = wbase + (size_t)(nt * 128 + row) * I_DIM + cg * 8;
    }
    const u16* srcA[2];
    #pragma unroll
    for (int j = 0; j < 2; ++j) {
        int s = j * 256 + tid;
        int row = s >> 3, c = s & 7, cg = c ^ (row & 7);
        int p = ptok[row];
        srcA[j] = (p >= 0) ? hq + (size_t)p * I_DIM + cg * 8 : zbuf;
    }

    int idxA[2][2], idxB[4][2];
    #pragma unroll
    for (int fm = 0; fm < 2; ++fm) {
        int ar = m * 32 + fm * 16 + l15;
        #pragma unroll
        for (int kg = 0; kg < 2; ++kg)
            idxA[fm][kg] = 8192 + ar * 64 + (((kg * 4 + l4) ^ (ar & 7)) * 8);
    }
    #pragma unroll
    for (int nf = 0; nf < 4; ++nf) {
        int br = q * 64 + nf * 16 + l15;
        #pragma unroll
        for (int kg = 0; kg < 2; ++kg)
            idxB[nf][kg] = br * 64 + (((kg * 4 + l4) ^ (br & 7)) * 8);
    }

    auto stage = [&](int buf) {
        #pragma unroll
        for (int j = 0; j < 4; ++j) { GLDS(srcB[j], &sm[buf][j * 2048 + tid * 8]); srcB[j] += 64; }
        #pragma unroll
        for (int j = 0; j < 2; ++j) { GLDS(srcA[j], &sm[buf][8192 + j * 2048 + tid * 8]); srcA[j] += 64; }
    };

    f4v master[2][4], part[2][4];
    #pragma unroll
    for (int a = 0; a < 2; ++a)
        #pragma unroll
        for (int b = 0; b < 4; ++b) { master[a][b] = (f4v){0,0,0,0}; part[a][b] = (f4v){0,0,0,0}; }

    const float* swp = sdn + (e * 8 + nt) * 4;

    stage(0);
    __syncthreads();

    for (int t = 0; t < 8; ++t) {
        if (t < 7) stage((t + 1) & 1);
        const u16* buf = &sm[t & 1][0];
        #pragma unroll
        for (int kg = 0; kg < 2; ++kg) {
            s8v a0 = *(const s8v*)&buf[idxA[0][kg]];
            s8v a1 = *(const s8v*)&buf[idxA[1][kg]];
            #pragma unroll
            for (int nf = 0; nf < 4; ++nf) {
                s8v b = *(const s8v*)&buf[idxB[nf][kg]];
                part[0][nf] = __builtin_amdgcn_mfma_f32_16x16x32_bf16(a0, b, part[0][nf], 0, 0, 0);
                part[1][nf] = __builtin_amdgcn_mfma_f32_16x16x32_bf16(a1, b, part[1][nf], 0, 0, 0);
            }
        }
        if (t & 1) {
            int kb = t >> 1;
            float sw = swp[kb];
            #pragma unroll
            for (int fm = 0; fm < 2; ++fm) {
                float c0 = hs_l[m * 32 + fm * 16 + l4 * 4 + 0][kb] * sw;
                float c1 = hs_l[m * 32 + fm * 16 + l4 * 4 + 1][kb] * sw;
                float c2 = hs_l[m * 32 + fm * 16 + l4 * 4 + 2][kb] * sw;
                float c3 = hs_l[m * 32 + fm * 16 + l4 * 4 + 3][kb] * sw;
                #pragma unroll
                for (int nf = 0; nf < 4; ++nf) {
                    master[fm][nf][0] += c0 * part[fm][nf][0];
                    master[fm][nf][1] += c1 * part[fm][nf][1];
                    master[fm][nf][2] += c2 * part[fm][nf][2];
                    master[fm][nf][3] += c3 * part[fm][nf][3];
                    part[fm][nf] = (f4v){0,0,0,0};
                }
            }
        }
        __syncthreads();
    }

    #pragma unroll
    for (int fm = 0; fm < 2; ++fm)
        #pragma unroll
        for (int r = 0; r < 4; ++r) {
            int row = m * 32 + fm * 16 + l4 * 4 + r;
            int p = ptok[row];
            if (p < 0) continue;
            float rw = rw_l[row];
            float* drow = dout + (size_t)p * H_DIM + nt * 128 + q * 64;
            #pragma unroll
            for (int nf = 0; nf < 4; ++nf)
                drow[nf * 16 + l15] = rw * master[fm][nf][r];
        }
}

// ---------- K6: sum the 4 slot-partials per token ----------
__global__ void k_reduce(const float* __restrict__ dout, float* __restrict__ out) {
    int i = blockIdx.x * 256 + threadIdx.x;   // f32x4 index over T*H
    int t = i >> 8, h4 = i & 255;
    const float4* d = (const float4*)dout;
    float4 a = d[(size_t)(t * 4 + 0) * 256 + h4];
    float4 b = d[(size_t)(t * 4 + 1) * 256 + h4];
    float4 c = d[(size_t)(t * 4 + 2) * 256 + h4];
    float4 e = d[(size_t)(t * 4 + 3) * 256 + h4];
    float4 r;
    r.x = a.x + b.x + c.x + e.x;
    r.y = a.y + b.y + c.y + e.y;
    r.z = a.z + b.z + c.z + e.z;
    r.w = a.w + b.w + c.w + e.w;
    ((float4*)out)[i] = r;
}

extern "C" void kernel_launch(void* const* d_in, const int* in_sizes, int n_in,
                              void* d_out, int out_size, void* d_ws, size_t ws_size,
                              hipStream_t stream) {
    const float* hs_in = (const float*)d_in[0];
    const int*   tki = (const int*)d_in[1];
    const float* tkw = (const float*)d_in[2];
    const float* wgu = (const float*)d_in[3];
    const float* sgu = (const float*)d_in[4];
    const float* wdn = (const float*)d_in[5];
    const float* sdn = (const float*)d_in[6];
    float* out = (float*)d_out;

    char* ws = (char*)d_ws;
    const size_t MB = 1024 * 1024;
    u16*   wgu_bf = (u16*)(ws);                    // 32 MB; ALIASED by dout after k_gateup
    float* dout   = (float*)(ws);                  // 32 MB (NPAIR*H f32)
    u16*   wdn_bf = (u16*)(ws + 32 * MB);          // 16 MB
    u16*   xq     = (u16*)(ws + 48 * MB);          // 4 MB
    float* xs     = (float*)(ws + 52 * MB);        // 64 KB
    float* hbuf   = (float*)(ws + 53 * MB);        // 16 MB (NPAIR*I f32)
    u16*   hq     = (u16*)(ws + 69 * MB);          // 8 MB
    float* hs     = (float*)(ws + 77 * MB);        // 128 KB
    int*   counts = (int*)(ws + 78 * MB);          // 64 ints (zeroed below)
    u16*   zbuf   = (u16*)(ws + 78 * MB + 4096);   // 4 KB zeros (zeroed below)
    int*   lists  = (int*)(ws + 78 * MB + 65536);  // 512 KB

    // single memset covers counts (4 KB region) + zbuf (4 KB)
    hipMemsetAsync(ws + 78 * MB, 0, 8192, stream);

    k_prep<<<14336, 256, 0, stream>>>(wgu, wgu_bf, wdn, wdn_bf, hs_in, xq, xs,
                                      tki, counts, lists);
    k_gateup<<<2048, 256, 0, stream>>>(xq, xs, counts, lists, wgu_bf, sgu, zbuf, hbuf);
    k_quant_h<<<NPAIR, 128, 0, stream>>>(hbuf, hq, hs);
    k_down<<<2048, 256, 0, stream>>>(hq, hs, counts, lists, wdn_bf, sdn, tkw, zbuf, dout);
    k_reduce<<<T_TOK * H_DIM / 1024, 256, 0, stream>>>(dout, out);
}